// Round 4
// baseline (289.228 us; speedup 1.0000x reference)
//
#include <hip/hip_runtime.h>
#include <cstdint>
#include <cstddef>

typedef unsigned short u16;
typedef unsigned int u32;
typedef __bf16 bf16x8 __attribute__((ext_vector_type(8)));
typedef float f32x4 __attribute__((ext_vector_type(4)));

#define DEVI static __device__ __forceinline__

// round-to-nearest-even fp32 -> bf16
DEVI u16 f2bf(float f) {
  u32 u = __builtin_bit_cast(u32, f);
  u = (u + 0x7fffu + ((u >> 16) & 1u)) >> 16;
  return (u16)u;
}
DEVI float bf2f(u16 u) { return __builtin_bit_cast(float, (u32)u << 16); }

// async global->LDS, 16B per lane. LDS dest is wave-uniform base + lane*16.
DEVI void gll16(const void* gsrc, const void* ldst) {
  __builtin_amdgcn_global_load_lds(
      (const __attribute__((address_space(1))) u32*)(uintptr_t)gsrc,
      (__attribute__((address_space(3))) u32*)(u32)(uintptr_t)ldst, 16, 0, 0);
}

DEVI float wredsum(float v) {
  v += __shfl_xor(v, 32); v += __shfl_xor(v, 16); v += __shfl_xor(v, 8);
  v += __shfl_xor(v, 4);  v += __shfl_xor(v, 2);  v += __shfl_xor(v, 1);
  return v;
}

// raw s_barrier with compiler memory fences (no vmcnt drain!)
DEVI void barx() {
  asm volatile("" ::: "memory");
  __builtin_amdgcn_s_barrier();
  asm volatile("" ::: "memory");
}

// ---------------- transpose + cvt: fp32 [R][C] -> bf16 [C][R] ----------------
__global__ __launch_bounds__(256) void k_tcvt(const float* __restrict__ in, u16* __restrict__ out,
                                              int R, int C, long in_z, long out_z) {
  __shared__ float tile[32][33];
  const float* inp = in + (long)blockIdx.z * in_z;
  u16* outp = out + (long)blockIdx.z * out_z;
  int c0 = blockIdx.x * 32, r0 = blockIdx.y * 32;
  int tx = threadIdx.x & 31, ty = threadIdx.x >> 5;
#pragma unroll
  for (int i = 0; i < 4; ++i)
    tile[ty + i * 8][tx] = inp[(long)(r0 + ty + i * 8) * C + c0 + tx];
  __syncthreads();
#pragma unroll
  for (int i = 0; i < 4; ++i) {
    int cc = ty + i * 8;
    outp[(long)(c0 + cc) * R + r0 + tx] = f2bf(tile[tx][cc]);
  }
}

// ---------------- elementwise fp32 -> bf16 ----------------
__global__ __launch_bounds__(256) void k_cvt(const float* __restrict__ in, u16* __restrict__ out, int n4) {
  int i = blockIdx.x * 256 + threadIdx.x;
  if (i >= n4) return;
  float4 v = ((const float4*)in)[i];
  ushort4 o;
  o.x = f2bf(v.x); o.y = f2bf(v.y); o.z = f2bf(v.z); o.w = f2bf(v.w);
  ((ushort4*)out)[i] = o;
}

// ============ ring-4 deep-pipelined bf16 GEMM ============
// C = A[M][K] * Bt[N][K]^T (+bias). Tile 256x256, BK=32, 8 waves (2M x 4N),
// per-wave 128x64 output (acc[8][4]). LDS 128KB = ring of 4 K-tiles x
// (A 16KB + B 16KB). K-major LDS layout [g][256 rows][16B] -> both gll16
// staging and ds_read_b128 are 2-way-bank-free (no swizzle needed).
// Per K-tile: 2 phases x 16 MFMA; stage A(t+3) in Ph1, B(t+3) in Ph2 (ring
// distance 3 = 4-phase prefetch lead); ONE vmcnt(8) per K-tile in Ph2
// (tail: 8 -> 4 -> 0); one s_barrier per phase; setprio around MFMA.
// Split-K via z-slice: partial output at base + z*pofs (elements).
// EPI: 0 = fp32 out, 1 = bf16 out (+bias), 2 = exact-GELU -> bf16 (+bias)
template <int EPI>
__global__ __launch_bounds__(512, 2) void k_gemm9(const u16* __restrict__ A, const u16* __restrict__ Bt,
                                                  const float* __restrict__ bias, void* __restrict__ Cout,
                                                  long pofs, int M, int N, int K, int Kc) {
  __shared__ __align__(16) u16 lds[65536];  // 128 KB
  char* Lc = (char*)&lds[0];
  const int tid = threadIdx.x;
  const int lane = tid & 63, wid = tid >> 6;
  const int wr = wid >> 2, wc = wid & 3;   // 2 M-waves x 4 N-waves
  const int g = lane >> 4, r16 = lane & 15;

  // bijective XCD swizzle (grid % 8 == 0 for all launches)
  const int gx = N >> 8, gy = M >> 8;
  const int cpx = (int)gridDim.x >> 3;
  int bb = (int)blockIdx.x;
  int id = (bb & 7) * cpx + (bb >> 3);
  const int gxy = gx * gy;
  const int bz = id / gxy;
  int rr2 = id - bz * gxy;
  const int by = rr2 / gx;
  const int bx = rr2 - by * gx;
  const long row0 = (long)by * 256;
  const long col0 = (long)bx * 256;
  const long kbeg = (long)bz * Kc;
  const int nk = Kc >> 5;  // K-tiles of 32 (nk >= 3)

  const size_t KB = (size_t)K * 2;  // global row stride in bytes
  const char* Ab = (const char*)A + (size_t)row0 * KB + (size_t)kbeg * 2;
  const char* Bb = (const char*)Bt + (size_t)col0 * KB + (size_t)kbeg * 2;

  // stage one 16KB unit (K-major [g2][256 rows][16B]): 2 gll16/thread.
  // dest granule gi = i_*512 + tid; g2 = gi>>8, row = gi&255; src 16B = global
  // row 'row', K-bytes [g2*16, g2*16+16) of the 64B-wide K-tile column.
#define STAGE9(gb, ldsoff)                                                       \
  do {                                                                           \
    _Pragma("unroll") for (int i_ = 0; i_ < 2; ++i_) {                           \
      int g2_ = i_ * 2 + (tid >> 8);                                             \
      int row_ = tid & 255;                                                      \
      gll16((gb) + (size_t)row_ * KB + g2_ * 16,                                 \
            Lc + (ldsoff) + i_ * 8192 + tid * 16);                               \
    }                                                                            \
  } while (0)

  f32x4 acc[8][4];
#pragma unroll
  for (int i = 0; i < 8; ++i)
#pragma unroll
    for (int j = 0; j < 4; ++j) acc[i][j] = {0.f, 0.f, 0.f, 0.f};

  // prologue: stage tiles 0,1,2 (A,B each) into ring slots 0,1,2
  STAGE9(Ab, 0);            STAGE9(Bb, 16384);
  STAGE9(Ab + 64, 32768);   STAGE9(Bb + 64, 32768 + 16384);
  STAGE9(Ab + 128, 65536);  STAGE9(Bb + 128, 65536 + 16384);
  asm volatile("s_waitcnt vmcnt(8)" ::: "memory");  // tile0 resident; 1,2 in flight
  barx();

  const int ard = (wr * 128 + r16) * 16;  // + m*256 within [g][row][16B]
  const int brd = (wc * 64 + r16) * 16;   // + n*256

  for (int t = 0; t < nk; ++t) {
    const char* bufA = Lc + (size_t)(t & 3) * 32768;
    const char* bufB = bufA + 16384;
    // -------- Phase 1: read A m0-3 + B n0-3; stage A(t+3); MFMA m0-3 --------
    bf16x8 aF[4], bF[4];
#pragma unroll
    for (int m = 0; m < 4; ++m)
      aF[m] = *(const bf16x8*)(bufA + g * 4096 + ard + m * 256);
#pragma unroll
    for (int n = 0; n < 4; ++n)
      bF[n] = *(const bf16x8*)(bufB + g * 4096 + brd + n * 256);
    if (t + 3 < nk) STAGE9(Ab + (size_t)(t + 3) * 64, ((t + 3) & 3) * 32768);
    __builtin_amdgcn_s_setprio(1);
#pragma unroll
    for (int m = 0; m < 4; ++m)
#pragma unroll
      for (int n = 0; n < 4; ++n)
        acc[m][n] = __builtin_amdgcn_mfma_f32_16x16x32_bf16(aF[m], bF[n], acc[m][n], 0, 0, 0);
    __builtin_amdgcn_s_setprio(0);
    barx();
    // -------- Phase 2: read A m4-7; stage B(t+3); counted vmcnt; MFMA m4-7 --------
    bf16x8 aG[4];
#pragma unroll
    for (int m = 0; m < 4; ++m)
      aG[m] = *(const bf16x8*)(bufA + g * 4096 + ard + (m + 4) * 256);
    if (t + 3 < nk) STAGE9(Bb + (size_t)(t + 3) * 64, ((t + 3) & 3) * 32768 + 16384);
    if (t < nk - 3) {
      asm volatile("s_waitcnt vmcnt(8)" ::: "memory");   // tile t+1 resident
    } else if (t == nk - 3) {
      asm volatile("s_waitcnt vmcnt(4)" ::: "memory");
    } else if (t == nk - 2) {
      asm volatile("s_waitcnt vmcnt(0)" ::: "memory");   // final drain
    }
    __builtin_amdgcn_s_setprio(1);
#pragma unroll
    for (int m = 0; m < 4; ++m)
#pragma unroll
      for (int n = 0; n < 4; ++n)
        acc[m + 4][n] = __builtin_amdgcn_mfma_f32_16x16x32_bf16(aG[m], bF[n], acc[m + 4][n], 0, 0, 0);
    __builtin_amdgcn_s_setprio(0);
    barx();
  }
#undef STAGE9

  // epilogue: C/D mapping col=lane&15, row=(lane>>4)*4+j
  float* outf = (float*)Cout + (long)bz * pofs;
  u16* outh = (u16*)Cout + (long)bz * pofs;
#pragma unroll
  for (int n = 0; n < 4; ++n) {
    long col = col0 + wc * 64 + n * 16 + r16;
    float bv = bias ? bias[col] : 0.f;
#pragma unroll
    for (int m = 0; m < 8; ++m) {
      long rowb = row0 + wr * 128 + m * 16 + g * 4;
#pragma unroll
      for (int j = 0; j < 4; ++j) {
        float v = acc[m][n][j] + bv;
        size_t off = (size_t)(rowb + j) * N + col;
        if (EPI == 0) {
          outf[off] = v;
        } else if (EPI == 1) {
          outh[off] = f2bf(v);
        } else {
          float gl = 0.5f * v * (1.f + erff(v * 0.70710678118f));
          outh[off] = f2bf(gl);
        }
      }
    }
  }
}

// ---------------- build V^T: qkvb[token][2048+h*64+p] -> vt[(b,h)][p][s] ----------------
__global__ __launch_bounds__(256) void k_build_vt(const u16* __restrict__ qkvb, u16* __restrict__ vt) {
  __shared__ u16 tile[32][33];
  int z = blockIdx.z, b = z >> 4, h = z & 15;
  int p0 = blockIdx.x * 32, s0 = blockIdx.y * 32;
  int tx = threadIdx.x & 31, ty = threadIdx.x >> 5;
#pragma unroll
  for (int i = 0; i < 4; ++i) {
    int s = s0 + ty + i * 8;
    tile[ty + i * 8][tx] = qkvb[(size_t)(b * 512 + s) * 3072 + 2048 + h * 64 + p0 + tx];
  }
  __syncthreads();
#pragma unroll
  for (int i = 0; i < 4; ++i) {
    int p = ty + i * 8;
    vt[((size_t)z * 64 + p0 + p) * 512 + s0 + tx] = tile[tx][p];
  }
}

// ---------------- fused flash attention ----------------
__global__ __launch_bounds__(256) void k_attn(const u16* __restrict__ qkvb, const u16* __restrict__ vt,
                                              u16* __restrict__ ctxb) {
  __shared__ __align__(16) u16 Qs[64 * 64];
  __shared__ __align__(16) u16 Ks[64 * 64];
  __shared__ __align__(16) u16 Vts[64 * 64];
  __shared__ __align__(16) u16 Ps[4 * 16 * 64];
  const int tid = threadIdx.x, lane = tid & 63, wid = tid >> 6;
  const int g = lane >> 4, r16 = lane & 15;
  const int z = blockIdx.y, b = z >> 4, h = z & 15;
  const int qt = blockIdx.x;
  const float CF = 0.125f * 1.44269504089f;

#pragma unroll
  for (int it = 0; it < 2; ++it) {
    int q = it * 4096 + tid * 16;
    int row = q >> 7, colb = q & 127;
    int scol = colb ^ ((row & 7) << 4);
    gll16((const char*)qkvb + ((size_t)(b * 512 + qt * 64 + row) * 3072 + h * 64) * 2 + scol,
          (const char*)Qs + it * 4096 + wid * 1024);
  }
  __syncthreads();
  bf16x8 aq[2];
  {
    int rowl = wid * 16 + r16;
#pragma unroll
    for (int kk = 0; kk < 2; ++kk)
      aq[kk] = *(const bf16x8*)(Qs + rowl * 64 + ((kk * 32 + g * 8) ^ ((rowl & 7) << 3)));
  }

  f32x4 o[4];
#pragma unroll
  for (int pi = 0; pi < 4; ++pi) o[pi] = {0.f, 0.f, 0.f, 0.f};
  float m4[4], l4[4];
#pragma unroll
  for (int j = 0; j < 4; ++j) { m4[j] = -1e30f; l4[j] = 0.f; }

  for (int kt = 0; kt < 8; ++kt) {
#pragma unroll
    for (int it = 0; it < 2; ++it) {
      int q = it * 4096 + tid * 16;
      int row = q >> 7, colb = q & 127;
      int scol = colb ^ ((row & 7) << 4);
      gll16((const char*)qkvb + ((size_t)(b * 512 + kt * 64 + row) * 3072 + 1024 + h * 64) * 2 + scol,
            (const char*)Ks + it * 4096 + wid * 1024);
      gll16((const char*)vt + ((size_t)(z * 64 + row) * 512 + kt * 64) * 2 + scol,
            (const char*)Vts + it * 4096 + wid * 1024);
    }
    __syncthreads();

    f32x4 s[4];
#pragma unroll
    for (int nj = 0; nj < 4; ++nj) s[nj] = {0.f, 0.f, 0.f, 0.f};
#pragma unroll
    for (int kk = 0; kk < 2; ++kk) {
#pragma unroll
      for (int nj = 0; nj < 4; ++nj) {
        int rowk = nj * 16 + r16;
        bf16x8 bk = *(const bf16x8*)(Ks + rowk * 64 + ((kk * 32 + g * 8) ^ ((rowk & 7) << 3)));
        s[nj] = __builtin_amdgcn_mfma_f32_16x16x32_bf16(aq[kk], bk, s[nj], 0, 0, 0);
      }
    }

    float scale[4];
#pragma unroll
    for (int j = 0; j < 4; ++j) {
      float pm = fmaxf(fmaxf(s[0][j], s[1][j]), fmaxf(s[2][j], s[3][j]));
      pm = fmaxf(pm, __shfl_xor(pm, 1));
      pm = fmaxf(pm, __shfl_xor(pm, 2));
      pm = fmaxf(pm, __shfl_xor(pm, 4));
      pm = fmaxf(pm, __shfl_xor(pm, 8));
      float mn = fmaxf(m4[j], pm);
      scale[j] = exp2f((m4[j] - mn) * CF);
      m4[j] = mn;
      int rowp = g * 4 + j;
      u16* pbase = Ps + wid * 1024 + rowp * 64;
      int sw = (rowp & 7) << 3;
      float ps = 0.f;
#pragma unroll
      for (int nj = 0; nj < 4; ++nj) {
        float p = exp2f((s[nj][j] - mn) * CF);
        ps += p;
        pbase[(nj * 16 + r16) ^ sw] = f2bf(p);
      }
      ps += __shfl_xor(ps, 1); ps += __shfl_xor(ps, 2);
      ps += __shfl_xor(ps, 4); ps += __shfl_xor(ps, 8);
      l4[j] = l4[j] * scale[j] + ps;
    }
#pragma unroll
    for (int pi = 0; pi < 4; ++pi)
#pragma unroll
      for (int j = 0; j < 4; ++j) o[pi][j] *= scale[j];

    asm volatile("s_waitcnt lgkmcnt(0)" ::: "memory");

#pragma unroll
    for (int kk = 0; kk < 2; ++kk) {
      bf16x8 ap = *(const bf16x8*)(Ps + wid * 1024 + r16 * 64 + ((kk * 32 + g * 8) ^ ((r16 & 7) << 3)));
#pragma unroll
      for (int pi = 0; pi < 4; ++pi) {
        int rowv = pi * 16 + r16;
        bf16x8 bv = *(const bf16x8*)(Vts + rowv * 64 + ((kk * 32 + g * 8) ^ ((rowv & 7) << 3)));
        o[pi] = __builtin_amdgcn_mfma_f32_16x16x32_bf16(ap, bv, o[pi], 0, 0, 0);
      }
    }
    __syncthreads();
  }

#pragma unroll
  for (int j = 0; j < 4; ++j) {
    float inv = 1.f / l4[j];
    int token = b * 512 + qt * 64 + wid * 16 + g * 4 + j;
#pragma unroll
    for (int pi = 0; pi < 4; ++pi)
      ctxb[(size_t)token * 1024 + h * 64 + pi * 16 + r16] = f2bf(o[pi][j] * inv);
  }
}

// ---------------- fused (4 bf16 partials) + bias + residual + LayerNorm ----------------
// v[c] = sum_z p[z*pofs + row*1024 + c] + res[row][c] + bvec[c];  out = LN(v)
__global__ __launch_bounds__(256) void k_ln4(const u16* __restrict__ p, long pofs,
                                             const float* __restrict__ res, const float* __restrict__ bvec,
                                             const float* __restrict__ gamma, const float* __restrict__ beta,
                                             float* __restrict__ outf, u16* __restrict__ outb) {
  __shared__ float sb[8];
  int row = blockIdx.x, t = threadIdx.x, lane = t & 63, wid = t >> 6;
  const size_t rb = (size_t)row * 1024 + t * 4;
  float4 rv = *(const float4*)(res + rb);
  float4 bb = *(const float4*)(bvec + t * 4);
  float v[4] = {rv.x + bb.x, rv.y + bb.y, rv.z + bb.z, rv.w + bb.w};
#pragma unroll
  for (int z = 0; z < 4; ++z) {
    ushort4 u = *(const ushort4*)(p + (size_t)z * pofs + rb);
    v[0] += bf2f(u.x); v[1] += bf2f(u.y); v[2] += bf2f(u.z); v[3] += bf2f(u.w);
  }
  float s = v[0] + v[1] + v[2] + v[3];
  s = wredsum(s);
  if (lane == 0) sb[wid] = s;
  __syncthreads();
  float mu = (sb[0] + sb[1] + sb[2] + sb[3]) * (1.f / 1024.f);
  float q = 0.f;
#pragma unroll
  for (int i = 0; i < 4; ++i) { float d = v[i] - mu; q += d * d; }
  q = wredsum(q);
  if (lane == 0) sb[4 + wid] = q;
  __syncthreads();
  float rstd = rsqrtf((sb[4] + sb[5] + sb[6] + sb[7]) * (1.f / 1024.f) + 1e-5f);
  float4 gv = *(const float4*)(gamma + t * 4);
  float4 bt = *(const float4*)(beta + t * 4);
  float ov[4];
  ov[0] = (v[0] - mu) * rstd * gv.x + bt.x;
  ov[1] = (v[1] - mu) * rstd * gv.y + bt.y;
  ov[2] = (v[2] - mu) * rstd * gv.z + bt.z;
  ov[3] = (v[3] - mu) * rstd * gv.w + bt.w;
  *(float4*)(outf + rb) = {ov[0], ov[1], ov[2], ov[3]};
  if (outb) {
    ushort4 ob = {f2bf(ov[0]), f2bf(ov[1]), f2bf(ov[2]), f2bf(ov[3])};
    *(ushort4*)(outb + rb) = ob;
  }
}

// ---------------- orchestration ----------------
// Workspace map (MB), time-multiplexed:
//   [0,6)   wqkvb (dead after qkv)
//   [6,8)   woutb (dead after attn_out)
//   [8,16)  wffn1b (dead after ffn1)
//   [16,24) free
//   [24,32) xb -> ctxb -> r1b
//   [32,56) qkvb -> qp0..2 -> hb
//   [56,64) vt -> qp3 -> hb
//   [64,72) free
//   [72,80) wffn2b (live until ffn2)
//   qp0..3 (attn_out bf16 partials, stride 8MB): [32,64)
//   pp0..3 (ffn2 bf16 partials, stride 8MB): [0,32)
//   r1 fp32 lives in d_out. Peak 80 MB.
extern "C" void kernel_launch(void* const* d_in, const int* in_sizes, int n_in,
                              void* d_out, int out_size, void* d_ws, size_t ws_size,
                              hipStream_t stream) {
  const float* x      = (const float*)d_in[0];
  const float* w_qkv  = (const float*)d_in[1];
  const float* b_qkv  = (const float*)d_in[2];
  const float* w_out  = (const float*)d_in[3];
  const float* b_out  = (const float*)d_in[4];
  const float* ln1s   = (const float*)d_in[5];
  const float* ln1b   = (const float*)d_in[6];
  const float* w_ffn1 = (const float*)d_in[7];
  const float* b_ffn1 = (const float*)d_in[8];
  const float* w_ffn2 = (const float*)d_in[9];
  const float* b_ffn2 = (const float*)d_in[10];
  const float* ln2s   = (const float*)d_in[11];
  const float* ln2b   = (const float*)d_in[12];

  char* ws = (char*)d_ws;
  const size_t MB = 1024 * 1024;
  u16* wqkvb   = (u16*)(ws + 0 * MB);
  u16* woutb   = (u16*)(ws + 6 * MB);
  u16* wffn1b  = (u16*)(ws + 8 * MB);
  u16* wffn2b  = (u16*)(ws + 72 * MB);
  u16* xb      = (u16*)(ws + 24 * MB);
  u16* ctxb    = xb;
  u16* r1b     = xb;
  u16* qkvb    = (u16*)(ws + 32 * MB);
  u16* vt      = (u16*)(ws + 56 * MB);
  u16* qp      = (u16*)(ws + 32 * MB);   // 4 bf16 partials, stride 8MB
  u16* hb      = (u16*)(ws + 32 * MB);
  u16* pp      = (u16*)(ws + 0 * MB);    // 4 bf16 partials, stride 8MB
  float* r1    = (float*)d_out;
  float* outp  = (float*)d_out;
  const long PSTRIDE = 4096L * 1024L;    // elements per bf16 partial (8MB)

  // pack weights (transpose to [N][K] bf16)
  k_tcvt<<<dim3(32, 32, 3), 256, 0, stream>>>(w_qkv, wqkvb, 1024, 1024, 1024 * 1024, 1024 * 1024);
  k_tcvt<<<dim3(32, 32, 1), 256, 0, stream>>>(w_out, woutb, 1024, 1024, 0, 0);
  k_tcvt<<<dim3(128, 32, 1), 256, 0, stream>>>(w_ffn1, wffn1b, 1024, 4096, 0, 0);
  k_tcvt<<<dim3(32, 128, 1), 256, 0, stream>>>(w_ffn2, wffn2b, 4096, 1024, 0, 0);
  k_cvt<<<4096, 256, 0, stream>>>(x, xb, 1048576);

  // qkv = x @ w_qkv + b_qkv  (bf16 out): grid 12x16 = 192 blocks, nk=32
  k_gemm9<1><<<dim3(12 * 16), 512, 0, stream>>>(xb, wqkvb, b_qkv, qkvb, 0, 4096, 3072, 1024, 1024);
  k_build_vt<<<dim3(2, 16, 128), 256, 0, stream>>>(qkvb, vt);
  k_attn<<<dim3(8, 128), 256, 0, stream>>>(qkvb, vt, ctxb);

  // attn_out partials = ctx @ w_out (split-K=4, bf16 partials qp0..3, nk=8)
  k_gemm9<1><<<dim3(4 * 16 * 4), 512, 0, stream>>>(ctxb, woutb, nullptr, qp, PSTRIDE,
                                                   4096, 1024, 1024, 256);
  // r1 = LN(x + sum(qp) + b_out) -> fp32 (d_out) + bf16
  k_ln4<<<4096, 256, 0, stream>>>(qp, PSTRIDE, x, b_out, ln1s, ln1b, r1, r1b);

  // h = gelu(r1 @ w_ffn1 + b_ffn1): grid 16x16 = 256 blocks, nk=32
  k_gemm9<2><<<dim3(16 * 16), 512, 0, stream>>>(r1b, wffn1b, b_ffn1, hb, 0, 4096, 4096, 1024, 1024);

  // ffn2 partials = h @ w_ffn2 (split-K=4, bf16 partials pp0..3, nk=32)
  k_gemm9<1><<<dim3(4 * 16 * 4), 512, 0, stream>>>(hb, wffn2b, nullptr, pp, PSTRIDE,
                                                   4096, 1024, 4096, 1024);
  // out = LN(r1 + sum(pp) + b_ffn2)
  k_ln4<<<4096, 256, 0, stream>>>(pp, PSTRIDE, r1, b_ffn2, ln2s, ln2b, outp, (u16*)nullptr);
}

// Round 6
// 285.833 us; speedup vs baseline: 1.0119x; 1.0119x over previous
//
#include <hip/hip_runtime.h>
#include <cstdint>
#include <cstddef>

typedef unsigned short u16;
typedef unsigned int u32;
typedef __bf16 bf16x8 __attribute__((ext_vector_type(8)));
typedef float f32x4 __attribute__((ext_vector_type(4)));

#define DEVI static __device__ __forceinline__

// round-to-nearest-even fp32 -> bf16
DEVI u16 f2bf(float f) {
  u32 u = __builtin_bit_cast(u32, f);
  u = (u + 0x7fffu + ((u >> 16) & 1u)) >> 16;
  return (u16)u;
}
DEVI float bf2f(u16 u) { return __builtin_bit_cast(float, (u32)u << 16); }

// async global->LDS, 16B per lane. LDS dest is wave-uniform base + lane*16.
DEVI void gll16(const void* gsrc, const void* ldst) {
  __builtin_amdgcn_global_load_lds(
      (const __attribute__((address_space(1))) u32*)(uintptr_t)gsrc,
      (__attribute__((address_space(3))) u32*)(u32)(uintptr_t)ldst, 16, 0, 0);
}

DEVI float wredsum(float v) {
  v += __shfl_xor(v, 32); v += __shfl_xor(v, 16); v += __shfl_xor(v, 8);
  v += __shfl_xor(v, 4);  v += __shfl_xor(v, 2);  v += __shfl_xor(v, 1);
  return v;
}

// raw s_barrier with compiler memory fences (no vmcnt drain!)
DEVI void barx() {
  asm volatile("" ::: "memory");
  __builtin_amdgcn_s_barrier();
  asm volatile("" ::: "memory");
}

// ---------------- transpose + cvt: fp32 [R][C] -> bf16 [C][R] ----------------
__global__ __launch_bounds__(256) void k_tcvt(const float* __restrict__ in, u16* __restrict__ out,
                                              int R, int C, long in_z, long out_z) {
  __shared__ float tile[32][33];
  const float* inp = in + (long)blockIdx.z * in_z;
  u16* outp = out + (long)blockIdx.z * out_z;
  int c0 = blockIdx.x * 32, r0 = blockIdx.y * 32;
  int tx = threadIdx.x & 31, ty = threadIdx.x >> 5;
#pragma unroll
  for (int i = 0; i < 4; ++i)
    tile[ty + i * 8][tx] = inp[(long)(r0 + ty + i * 8) * C + c0 + tx];
  __syncthreads();
#pragma unroll
  for (int i = 0; i < 4; ++i) {
    int cc = ty + i * 8;
    outp[(long)(c0 + cc) * R + r0 + tx] = f2bf(tile[tx][cc]);
  }
}

// ---------------- elementwise fp32 -> bf16 ----------------
__global__ __launch_bounds__(256) void k_cvt(const float* __restrict__ in, u16* __restrict__ out, int n4) {
  int i = blockIdx.x * 256 + threadIdx.x;
  if (i >= n4) return;
  float4 v = ((const float4*)in)[i];
  ushort4 o;
  o.x = f2bf(v.x); o.y = f2bf(v.y); o.z = f2bf(v.z); o.w = f2bf(v.w);
  ((ushort4*)out)[i] = o;
}

// ============ m201-style 8-phase bf16 GEMM (4 phases per BK=64 K-tile) ============
// C = A[M][K]*Bt[N][K]^T (+bias). Tile 256x256, 8 waves (2M x 4N), per-wave 128x64
// (acc[8][4]). LDS 128KB = 2 buf x {Aks0,Aks1,Bks0,Bks1} 16KB units, K-major
// granule layout [g2:4][256 rows][16B] -> staging + ds_read_b128 bank-conflict-free.
// Residency rule (per-wave vmcnt + cross-wave data => vmcnt BEFORE a joint
// barrier that precedes the ds_read):
//   prologue: 6 units; vmcnt(8); barrier      -> {Aks0,Bks0}(0) resident
//   P2 tail:  vmcnt(8) [nk-1: vmcnt(0)]       -> {Aks1,Bks1}(t) for P3
//   P4 tail:  vmcnt(8) [nk-2: 4; nk-1: skip]  -> {Aks0,Bks0}(t+1) for next P1
// Stage order: P1:Aks1(t+1) P2:Bks1(t+1) P3:Aks0(t+2) P4:Bks0(t+2).
// Split-K via z: output at base + z*pofs. EPI: 0=f32, 1=bf16(+bias), 2=GELU->bf16
template <int EPI>
__global__ __launch_bounds__(512, 2) void k_gemmA(const u16* __restrict__ A, const u16* __restrict__ Bt,
                                                  const float* __restrict__ bias, void* __restrict__ Cout,
                                                  long pofs, int M, int N, int K, int Kc) {
  __shared__ __align__(16) u16 lds[65536];  // 128 KB
  char* Lc = (char*)&lds[0];
  const int tid = threadIdx.x;
  const int lane = tid & 63, wid = tid >> 6;
  const int wr = wid >> 2, wc = wid & 3;   // 2 M-waves x 4 N-waves
  const int g = lane >> 4, r16 = lane & 15;

  // bijective XCD swizzle (grid % 8 == 0 for all launches)
  const int gx = N >> 8, gy = M >> 8;
  const int cpx = (int)gridDim.x >> 3;
  int bb = (int)blockIdx.x;
  int id = (bb & 7) * cpx + (bb >> 3);
  const int gxy = gx * gy;
  const int bz = id / gxy;
  int rr2 = id - bz * gxy;
  const int by = rr2 / gx;
  const int bx = rr2 - by * gx;
  const long row0 = (long)by * 256;
  const long col0 = (long)bx * 256;
  const long kbeg = (long)bz * Kc;
  const int nk = Kc >> 6;  // BK=64 K-tiles (nk >= 2)

  const size_t KB = (size_t)K * 2;  // global row stride in bytes
  const char* Ab = (const char*)A + (size_t)row0 * KB + (size_t)kbeg * 2;
  const char* Bb = (const char*)Bt + (size_t)col0 * KB + (size_t)kbeg * 2;

  // LDS unit offsets within a buffer
  const int UA0 = 0, UA1 = 16384, UB0 = 32768, UB1 = 49152;

  // stage one 16KB unit (K-major [g2][256 rows][16B]): 2 gll16/thread.
#define STG(gb, ldsoff)                                                          \
  do {                                                                           \
    _Pragma("unroll") for (int i_ = 0; i_ < 2; ++i_) {                           \
      int g2_ = i_ * 2 + (tid >> 8);                                             \
      int row_ = tid & 255;                                                      \
      gll16((gb) + (size_t)row_ * KB + g2_ * 16,                                 \
            Lc + (ldsoff) + i_ * 8192 + tid * 16);                               \
    }                                                                            \
  } while (0)

  f32x4 acc[8][4];
#pragma unroll
  for (int i = 0; i < 8; ++i)
#pragma unroll
    for (int j = 0; j < 4; ++j) acc[i][j] = {0.f, 0.f, 0.f, 0.f};

  // prologue: t0 {Aks0,Bks0,Aks1,Bks1} -> buf0; t1 {Aks0,Bks0} -> buf1 (12 loads)
  STG(Ab, UA0);             STG(Bb, UB0);
  STG(Ab + 64, UA1);        STG(Bb + 64, UB1);
  STG(Ab + 128, 65536 + UA0); STG(Bb + 128, 65536 + UB0);
  asm volatile("s_waitcnt vmcnt(8)" ::: "memory");  // {Aks0,Bks0}(0) resident
  barx();

  // per-thread ds_read bases (byte)
  const int ardA = (wr * 128 + r16) * 16;  // A: row = wr*128 + m*16 + r16
  const int brdB = (wc * 64 + r16) * 16;   // B: row = wc*64  + n*16 + r16
  const int gof = g * 4096;

  for (int t = 0; t < nk; ++t) {
    const int bof = (t & 1) * 65536;
    const int obof = 65536 - bof;
    const char* Base = Lc + bof;
    bf16x8 aF[4], bF[4], aG[4];
    // ====== P1: a[ks0][m0-3], b[ks0][n0-3]; stage Aks1(t+1); MFMA ======
#pragma unroll
    for (int m = 0; m < 4; ++m) aF[m] = *(const bf16x8*)(Base + UA0 + gof + ardA + m * 256);
#pragma unroll
    for (int n = 0; n < 4; ++n) bF[n] = *(const bf16x8*)(Base + UB0 + gof + brdB + n * 256);
    if (t + 1 < nk) STG(Ab + (size_t)(t + 1) * 128 + 64, obof + UA1);
    barx();
    __builtin_amdgcn_s_setprio(1);
#pragma unroll
    for (int m = 0; m < 4; ++m)
#pragma unroll
      for (int n = 0; n < 4; ++n)
        acc[m][n] = __builtin_amdgcn_mfma_f32_16x16x32_bf16(aF[m], bF[n], acc[m][n], 0, 0, 0);
    __builtin_amdgcn_s_setprio(0);
    barx();
    // ====== P2: a[ks0][m4-7]; stage Bks1(t+1); MFMA; vmcnt; endbar ======
#pragma unroll
    for (int m = 0; m < 4; ++m) aG[m] = *(const bf16x8*)(Base + UA0 + gof + ardA + (m + 4) * 256);
    if (t + 1 < nk) STG(Bb + (size_t)(t + 1) * 128 + 64, obof + UB1);
    barx();
    __builtin_amdgcn_s_setprio(1);
#pragma unroll
    for (int m = 0; m < 4; ++m)
#pragma unroll
      for (int n = 0; n < 4; ++n)
        acc[m + 4][n] = __builtin_amdgcn_mfma_f32_16x16x32_bf16(aG[m], bF[n], acc[m + 4][n], 0, 0, 0);
    __builtin_amdgcn_s_setprio(0);
    if (t < nk - 1) {
      asm volatile("s_waitcnt vmcnt(8)" ::: "memory");  // {Aks1,Bks1}(t) resident
    } else {
      asm volatile("s_waitcnt vmcnt(0)" ::: "memory");
    }
    barx();
    // ====== P3: a[ks1][m0-3], b[ks1][n0-3]; stage Aks0(t+2); MFMA ======
#pragma unroll
    for (int m = 0; m < 4; ++m) aF[m] = *(const bf16x8*)(Base + UA1 + gof + ardA + m * 256);
#pragma unroll
    for (int n = 0; n < 4; ++n) bF[n] = *(const bf16x8*)(Base + UB1 + gof + brdB + n * 256);
    if (t + 2 < nk) STG(Ab + (size_t)(t + 2) * 128, bof + UA0);
    barx();
    __builtin_amdgcn_s_setprio(1);
#pragma unroll
    for (int m = 0; m < 4; ++m)
#pragma unroll
      for (int n = 0; n < 4; ++n)
        acc[m][n] = __builtin_amdgcn_mfma_f32_16x16x32_bf16(aF[m], bF[n], acc[m][n], 0, 0, 0);
    __builtin_amdgcn_s_setprio(0);
    barx();
    // ====== P4: a[ks1][m4-7]; stage Bks0(t+2); MFMA; vmcnt; endbar ======
#pragma unroll
    for (int m = 0; m < 4; ++m) aG[m] = *(const bf16x8*)(Base + UA1 + gof + ardA + (m + 4) * 256);
    if (t + 2 < nk) STG(Bb + (size_t)(t + 2) * 128, bof + UB0);
    barx();
    __builtin_amdgcn_s_setprio(1);
#pragma unroll
    for (int m = 0; m < 4; ++m)
#pragma unroll
      for (int n = 0; n < 4; ++n)
        acc[m + 4][n] = __builtin_amdgcn_mfma_f32_16x16x32_bf16(aG[m], bF[n], acc[m + 4][n], 0, 0, 0);
    __builtin_amdgcn_s_setprio(0);
    if (t < nk - 2) {
      asm volatile("s_waitcnt vmcnt(8)" ::: "memory");  // {Aks0,Bks0}(t+1) resident
    } else if (t == nk - 2) {
      asm volatile("s_waitcnt vmcnt(4)" ::: "memory");
    }
    barx();
  }
#undef STG

  // epilogue: C/D mapping col=lane&15, row=(lane>>4)*4+j
  float* outf = (float*)Cout + (long)bz * pofs;
  u16* outh = (u16*)Cout + (long)bz * pofs;
#pragma unroll
  for (int n = 0; n < 4; ++n) {
    long col = col0 + wc * 64 + n * 16 + r16;
    float bv = bias ? bias[col] : 0.f;
#pragma unroll
    for (int m = 0; m < 8; ++m) {
      long rowb = row0 + wr * 128 + m * 16 + g * 4;
#pragma unroll
      for (int j = 0; j < 4; ++j) {
        float v = acc[m][n][j] + bv;
        size_t off = (size_t)(rowb + j) * N + col;
        if (EPI == 0) {
          outf[off] = v;
        } else if (EPI == 1) {
          outh[off] = f2bf(v);
        } else {
          float gl = 0.5f * v * (1.f + erff(v * 0.70710678118f));
          outh[off] = f2bf(gl);
        }
      }
    }
  }
}

// ---------------- build V^T: qkvb[token][2048+h*64+p] -> vt[(b,h)][p][s] ----------------
__global__ __launch_bounds__(256) void k_build_vt(const u16* __restrict__ qkvb, u16* __restrict__ vt) {
  __shared__ u16 tile[32][33];
  int z = blockIdx.z, b = z >> 4, h = z & 15;
  int p0 = blockIdx.x * 32, s0 = blockIdx.y * 32;
  int tx = threadIdx.x & 31, ty = threadIdx.x >> 5;
#pragma unroll
  for (int i = 0; i < 4; ++i) {
    int s = s0 + ty + i * 8;
    tile[ty + i * 8][tx] = qkvb[(size_t)(b * 512 + s) * 3072 + 2048 + h * 64 + p0 + tx];
  }
  __syncthreads();
#pragma unroll
  for (int i = 0; i < 4; ++i) {
    int p = ty + i * 8;
    vt[((size_t)z * 64 + p0 + p) * 512 + s0 + tx] = tile[tx][p];
  }
}

// ---------------- fused flash attention ----------------
__global__ __launch_bounds__(256) void k_attn(const u16* __restrict__ qkvb, const u16* __restrict__ vt,
                                              u16* __restrict__ ctxb) {
  __shared__ __align__(16) u16 Qs[64 * 64];
  __shared__ __align__(16) u16 Ks[64 * 64];
  __shared__ __align__(16) u16 Vts[64 * 64];
  __shared__ __align__(16) u16 Ps[4 * 16 * 64];
  const int tid = threadIdx.x, lane = tid & 63, wid = tid >> 6;
  const int g = lane >> 4, r16 = lane & 15;
  const int z = blockIdx.y, b = z >> 4, h = z & 15;
  const int qt = blockIdx.x;
  const float CF = 0.125f * 1.44269504089f;

#pragma unroll
  for (int it = 0; it < 2; ++it) {
    int q = it * 4096 + tid * 16;
    int row = q >> 7, colb = q & 127;
    int scol = colb ^ ((row & 7) << 4);
    gll16((const char*)qkvb + ((size_t)(b * 512 + qt * 64 + row) * 3072 + h * 64) * 2 + scol,
          (const char*)Qs + it * 4096 + wid * 1024);
  }
  __syncthreads();
  bf16x8 aq[2];
  {
    int rowl = wid * 16 + r16;
#pragma unroll
    for (int kk = 0; kk < 2; ++kk)
      aq[kk] = *(const bf16x8*)(Qs + rowl * 64 + ((kk * 32 + g * 8) ^ ((rowl & 7) << 3)));
  }

  f32x4 o[4];
#pragma unroll
  for (int pi = 0; pi < 4; ++pi) o[pi] = {0.f, 0.f, 0.f, 0.f};
  float m4[4], l4[4];
#pragma unroll
  for (int j = 0; j < 4; ++j) { m4[j] = -1e30f; l4[j] = 0.f; }

  for (int kt = 0; kt < 8; ++kt) {
#pragma unroll
    for (int it = 0; it < 2; ++it) {
      int q = it * 4096 + tid * 16;
      int row = q >> 7, colb = q & 127;
      int scol = colb ^ ((row & 7) << 4);
      gll16((const char*)qkvb + ((size_t)(b * 512 + kt * 64 + row) * 3072 + 1024 + h * 64) * 2 + scol,
            (const char*)Ks + it * 4096 + wid * 1024);
      gll16((const char*)vt + ((size_t)(z * 64 + row) * 512 + kt * 64) * 2 + scol,
            (const char*)Vts + it * 4096 + wid * 1024);
    }
    __syncthreads();

    f32x4 s[4];
#pragma unroll
    for (int nj = 0; nj < 4; ++nj) s[nj] = {0.f, 0.f, 0.f, 0.f};
#pragma unroll
    for (int kk = 0; kk < 2; ++kk) {
#pragma unroll
      for (int nj = 0; nj < 4; ++nj) {
        int rowk = nj * 16 + r16;
        bf16x8 bk = *(const bf16x8*)(Ks + rowk * 64 + ((kk * 32 + g * 8) ^ ((rowk & 7) << 3)));
        s[nj] = __builtin_amdgcn_mfma_f32_16x16x32_bf16(aq[kk], bk, s[nj], 0, 0, 0);
      }
    }

    float scale[4];
#pragma unroll
    for (int j = 0; j < 4; ++j) {
      float pm = fmaxf(fmaxf(s[0][j], s[1][j]), fmaxf(s[2][j], s[3][j]));
      pm = fmaxf(pm, __shfl_xor(pm, 1));
      pm = fmaxf(pm, __shfl_xor(pm, 2));
      pm = fmaxf(pm, __shfl_xor(pm, 4));
      pm = fmaxf(pm, __shfl_xor(pm, 8));
      float mn = fmaxf(m4[j], pm);
      scale[j] = exp2f((m4[j] - mn) * CF);
      m4[j] = mn;
      int rowp = g * 4 + j;
      u16* pbase = Ps + wid * 1024 + rowp * 64;
      int sw = (rowp & 7) << 3;
      float ps = 0.f;
#pragma unroll
      for (int nj = 0; nj < 4; ++nj) {
        float p = exp2f((s[nj][j] - mn) * CF);
        ps += p;
        pbase[(nj * 16 + r16) ^ sw] = f2bf(p);
      }
      ps += __shfl_xor(ps, 1); ps += __shfl_xor(ps, 2);
      ps += __shfl_xor(ps, 4); ps += __shfl_xor(ps, 8);
      l4[j] = l4[j] * scale[j] + ps;
    }
#pragma unroll
    for (int pi = 0; pi < 4; ++pi)
#pragma unroll
      for (int j = 0; j < 4; ++j) o[pi][j] *= scale[j];

    asm volatile("s_waitcnt lgkmcnt(0)" ::: "memory");

#pragma unroll
    for (int kk = 0; kk < 2; ++kk) {
      bf16x8 ap = *(const bf16x8*)(Ps + wid * 1024 + r16 * 64 + ((kk * 32 + g * 8) ^ ((r16 & 7) << 3)));
#pragma unroll
      for (int pi = 0; pi < 4; ++pi) {
        int rowv = pi * 16 + r16;
        bf16x8 bv = *(const bf16x8*)(Vts + rowv * 64 + ((kk * 32 + g * 8) ^ ((rowv & 7) << 3)));
        o[pi] = __builtin_amdgcn_mfma_f32_16x16x32_bf16(ap, bv, o[pi], 0, 0, 0);
      }
    }
    __syncthreads();
  }

#pragma unroll
  for (int j = 0; j < 4; ++j) {
    float inv = 1.f / l4[j];
    int token = b * 512 + qt * 64 + wid * 16 + g * 4 + j;
#pragma unroll
    for (int pi = 0; pi < 4; ++pi)
      ctxb[(size_t)token * 1024 + h * 64 + pi * 16 + r16] = f2bf(o[pi][j] * inv);
  }
}

// ---------------- fused (4 bf16 partials) + bias + residual + LayerNorm ----------------
__global__ __launch_bounds__(256) void k_ln4(const u16* __restrict__ p, long pofs,
                                             const float* __restrict__ res, const float* __restrict__ bvec,
                                             const float* __restrict__ gamma, const float* __restrict__ beta,
                                             float* __restrict__ outf, u16* __restrict__ outb) {
  __shared__ float sb[8];
  int row = blockIdx.x, t = threadIdx.x, lane = t & 63, wid = t >> 6;
  const size_t rb = (size_t)row * 1024 + t * 4;
  float4 rv = *(const float4*)(res + rb);
  float4 bb = *(const float4*)(bvec + t * 4);
  float v[4] = {rv.x + bb.x, rv.y + bb.y, rv.z + bb.z, rv.w + bb.w};
#pragma unroll
  for (int z = 0; z < 4; ++z) {
    ushort4 u = *(const ushort4*)(p + (size_t)z * pofs + rb);
    v[0] += bf2f(u.x); v[1] += bf2f(u.y); v[2] += bf2f(u.z); v[3] += bf2f(u.w);
  }
  float s = v[0] + v[1] + v[2] + v[3];
  s = wredsum(s);
  if (lane == 0) sb[wid] = s;
  __syncthreads();
  float mu = (sb[0] + sb[1] + sb[2] + sb[3]) * (1.f / 1024.f);
  float q = 0.f;
#pragma unroll
  for (int i = 0; i < 4; ++i) { float d = v[i] - mu; q += d * d; }
  q = wredsum(q);
  if (lane == 0) sb[4 + wid] = q;
  __syncthreads();
  float rstd = rsqrtf((sb[4] + sb[5] + sb[6] + sb[7]) * (1.f / 1024.f) + 1e-5f);
  float4 gv = *(const float4*)(gamma + t * 4);
  float4 bt = *(const float4*)(beta + t * 4);
  float ov[4];
  ov[0] = (v[0] - mu) * rstd * gv.x + bt.x;
  ov[1] = (v[1] - mu) * rstd * gv.y + bt.y;
  ov[2] = (v[2] - mu) * rstd * gv.z + bt.z;
  ov[3] = (v[3] - mu) * rstd * gv.w + bt.w;
  *(float4*)(outf + rb) = {ov[0], ov[1], ov[2], ov[3]};
  if (outb) {
    ushort4 ob = {f2bf(ov[0]), f2bf(ov[1]), f2bf(ov[2]), f2bf(ov[3])};
    *(ushort4*)(outb + rb) = ob;
  }
}

// ---------------- orchestration ----------------
// Workspace map (MB), time-multiplexed (R4 layout):
//   [0,6) wqkvb | [6,8) woutb | [8,16) wffn1b | [16,24) free | [24,32) xb/ctxb/r1b
//   [32,56) qkvb -> qp0..2 -> hb | [56,64) vt -> qp3 -> hb | [64,72) free
//   [72,80) wffn2b.  qp0..3 @ [32,64) stride 8MB; pp0..3 @ [0,32) stride 8MB.
//   r1 fp32 in d_out. Peak 80 MB.
extern "C" void kernel_launch(void* const* d_in, const int* in_sizes, int n_in,
                              void* d_out, int out_size, void* d_ws, size_t ws_size,
                              hipStream_t stream) {
  const float* x      = (const float*)d_in[0];
  const float* w_qkv  = (const float*)d_in[1];
  const float* b_qkv  = (const float*)d_in[2];
  const float* w_out  = (const float*)d_in[3];
  const float* b_out  = (const float*)d_in[4];
  const float* ln1s   = (const float*)d_in[5];
  const float* ln1b   = (const float*)d_in[6];
  const float* w_ffn1 = (const float*)d_in[7];
  const float* b_ffn1 = (const float*)d_in[8];
  const float* w_ffn2 = (const float*)d_in[9];
  const float* b_ffn2 = (const float*)d_in[10];
  const float* ln2s   = (const float*)d_in[11];
  const float* ln2b   = (const float*)d_in[12];

  char* ws = (char*)d_ws;
  const size_t MB = 1024 * 1024;
  u16* wqkvb   = (u16*)(ws + 0 * MB);
  u16* woutb   = (u16*)(ws + 6 * MB);
  u16* wffn1b  = (u16*)(ws + 8 * MB);
  u16* wffn2b  = (u16*)(ws + 72 * MB);
  u16* xb      = (u16*)(ws + 24 * MB);
  u16* ctxb    = xb;
  u16* r1b     = xb;
  u16* qkvb    = (u16*)(ws + 32 * MB);
  u16* vt      = (u16*)(ws + 56 * MB);
  u16* qp      = (u16*)(ws + 32 * MB);   // 4 bf16 partials, stride 8MB
  u16* hb      = (u16*)(ws + 32 * MB);
  u16* pp      = (u16*)(ws + 0 * MB);    // 4 bf16 partials, stride 8MB
  float* r1    = (float*)d_out;
  float* outp  = (float*)d_out;
  const long PSTRIDE = 4096L * 1024L;    // elements per bf16 partial (8MB)

  // pack weights (transpose to [N][K] bf16)
  k_tcvt<<<dim3(32, 32, 3), 256, 0, stream>>>(w_qkv, wqkvb, 1024, 1024, 1024 * 1024, 1024 * 1024);
  k_tcvt<<<dim3(32, 32, 1), 256, 0, stream>>>(w_out, woutb, 1024, 1024, 0, 0);
  k_tcvt<<<dim3(128, 32, 1), 256, 0, stream>>>(w_ffn1, wffn1b, 1024, 4096, 0, 0);
  k_tcvt<<<dim3(32, 128, 1), 256, 0, stream>>>(w_ffn2, wffn2b, 4096, 1024, 0, 0);
  k_cvt<<<4096, 256, 0, stream>>>(x, xb, 1048576);

  // qkv = x @ w_qkv + b_qkv  (bf16 out): grid 12x16 = 192 blocks, nk=16
  k_gemmA<1><<<dim3(12 * 16), 512, 0, stream>>>(xb, wqkvb, b_qkv, qkvb, 0, 4096, 3072, 1024, 1024);
  k_build_vt<<<dim3(2, 16, 128), 256, 0, stream>>>(qkvb, vt);
  k_attn<<<dim3(8, 128), 256, 0, stream>>>(qkvb, vt, ctxb);

  // attn_out partials = ctx @ w_out (split-K=4, bf16 partials qp0..3, nk=4)
  k_gemmA<1><<<dim3(4 * 16 * 4), 512, 0, stream>>>(ctxb, woutb, nullptr, qp, PSTRIDE,
                                                   4096, 1024, 1024, 256);
  // r1 = LN(x + sum(qp) + b_out) -> fp32 (d_out) + bf16
  k_ln4<<<4096, 256, 0, stream>>>(qp, PSTRIDE, x, b_out, ln1s, ln1b, r1, r1b);

  // h = gelu(r1 @ w_ffn1 + b_ffn1): grid 16x16 = 256 blocks, nk=16
  k_gemmA<2><<<dim3(16 * 16), 512, 0, stream>>>(r1b, wffn1b, b_ffn1, hb, 0, 4096, 4096, 1024, 1024);

  // ffn2 partials = h @ w_ffn2 (split-K=4, bf16 partials pp0..3, nk=16)
  k_gemmA<1><<<dim3(4 * 16 * 4), 512, 0, stream>>>(hb, wffn2b, nullptr, pp, PSTRIDE,
                                                   4096, 1024, 4096, 1024);
  // out = LN(r1 + sum(pp) + b_ffn2)
  k_ln4<<<4096, 256, 0, stream>>>(pp, PSTRIDE, r1, b_ffn2, ln2s, ln2b, outp, (u16*)nullptr);
}